// Round 16
// baseline (245.467 us; speedup 1.0000x reference)
//
#include <hip/hip_runtime.h>
#include <math.h>

#define BATCH 16
#define CDIM 256
#define HW 9216
#define RDIM 32
#define SPLITS 16
#define KSLAB (HW / SPLITS)   /* 576 */
#define KCH 32                /* gram k-columns per chunk */
#define NCH (KSLAB / KCH)     /* 18, even */

#define BN 64                 /* out_kernel n-tile */
#define BK 64                 /* out_kernel k-chunk */

typedef __attribute__((ext_vector_type(8))) short short8;
typedef __attribute__((ext_vector_type(4))) short short4_t;
typedef __attribute__((ext_vector_type(4))) float f32x4;
typedef __attribute__((ext_vector_type(8))) _Float16 half8;

__device__ __forceinline__ unsigned short bf16_rne(float x) {
    union { float f; unsigned u; } a; a.f = x;
    return (unsigned short)((a.u + 0x7fffu + ((a.u >> 16) & 1u)) >> 16);
}
__device__ __forceinline__ unsigned pack2(float lo, float hi) {
    return (unsigned)bf16_rne(lo) | ((unsigned)bf16_rne(hi) << 16);
}

// Non-draining barrier: ds ops visible, global loads STAY IN FLIGHT.
__device__ __forceinline__ void lds_barrier() {
    asm volatile("s_waitcnt lgkmcnt(0)" ::: "memory");
    __builtin_amdgcn_s_barrier();
}

// gram fp16 tile [256 rows][32 k], row stride 64 B (2-way max conflicts).
__device__ __forceinline__ int gswz16(int row, int k) {
    int byte = (row << 6) + (k << 1);
    byte ^= (((row >> 1) ^ (row >> 3)) & 3) << 4;
    return byte >> 1;
}
// swizzle for [*][64] bf16 tiles (row stride 128 B); byte offset.
__device__ __forceinline__ int bofs(int row, int k) {
    return (((row) << 7) | ((k) << 1)) ^ (((row ^ (row >> 2)) & 7) << 4);
}

// ---------------- K1: energy partials = v v^T (split-K, fp16 MFMA) ----------
// UNCHANGED from R14/R15 (proven): NT partial stores; atomic fallback.
template <bool ATOMIC>
__global__ __launch_bounds__(1024) void gram_kernel(const float* __restrict__ x,
                                                    float* __restrict__ part,
                                                    float* __restrict__ pooled) {
    int split = blockIdx.x;
    int b     = blockIdx.y;
    const float* v = x + (size_t)b * CDIM * HW;
    int kbase0 = split * KSLAB;

    __shared__ _Float16 lds[2][CDIM * KCH];   // 2 x 16 KB

    int t    = threadIdx.x;
    int row  = t >> 2;
    int kq   = t & 3;
    int lane = t & 63;
    int wave = t >> 6;
    int wr   = wave >> 2, wc = wave & 3;
    int lhi  = lane >> 4, llo = lane & 15;

    const float4* vrow = (const float4*)(v + (size_t)row * HW);

    f32x4 acc[4][4];
    #pragma unroll
    for (int i = 0; i < 4; ++i)
        #pragma unroll
        for (int j = 0; j < 4; ++j)
            acc[i][j] = (f32x4){0.f, 0.f, 0.f, 0.f};

    float psum = 0.f;
    float4 fa0, fa1, fb0, fb1;

    {
        int kb0 = kbase0;
        fa0 = vrow[(kb0 >> 2) + kq * 2];
        fa1 = vrow[(kb0 >> 2) + kq * 2 + 1];
        int kb1 = kbase0 + KCH;
        fb0 = vrow[(kb1 >> 2) + kq * 2];
        fb1 = vrow[(kb1 >> 2) + kq * 2 + 1];
    }

    auto body = [&](float4& g0, float4& g1, _Float16* buf, int ch) {
        float vals[8] = { g0.x, g0.y, g0.z, g0.w, g1.x, g1.y, g1.z, g1.w };
        half8 h;
        #pragma unroll
        for (int j = 0; j < 8; ++j) {
            psum += vals[j];
            h[j] = (_Float16)vals[j];
        }
        *(half8*)&buf[gswz16(row, kq * 8)] = h;
        if (ch + 2 < NCH) {
            int kb = kbase0 + (ch + 2) * KCH;
            g0 = vrow[(kb >> 2) + kq * 2];
            g1 = vrow[(kb >> 2) + kq * 2 + 1];
        }
        lds_barrier();

        half8 A[4], B[4];
        #pragma unroll
        for (int rb = 0; rb < 4; ++rb)
            A[rb] = *(const half8*)&buf[gswz16(wr * 64 + rb * 16 + llo, lhi * 8)];
        #pragma unroll
        for (int cb = 0; cb < 4; ++cb)
            B[cb] = *(const half8*)&buf[gswz16(wc * 64 + cb * 16 + llo, lhi * 8)];

        __builtin_amdgcn_s_setprio(1);
        #pragma unroll
        for (int rb = 0; rb < 4; ++rb)
            #pragma unroll
            for (int cb = 0; cb < 4; ++cb)
                acc[rb][cb] = __builtin_amdgcn_mfma_f32_16x16x32_f16(A[rb], B[cb], acc[rb][cb], 0, 0, 0);
        __builtin_amdgcn_s_setprio(0);
    };

    #pragma unroll 1
    for (int it = 0; it < NCH / 2; ++it) {
        body(fa0, fa1, (_Float16*)lds[0], it * 2);
        body(fb0, fb1, (_Float16*)lds[1], it * 2 + 1);
    }

    psum += __shfl_xor(psum, 1);
    psum += __shfl_xor(psum, 2);
    if (kq == 0) atomicAdd(&pooled[b * CDIM + row], psum);

    if (ATOMIC) {
        #pragma unroll
        for (int rb = 0; rb < 4; ++rb) {
            int r0 = wr * 64 + rb * 16 + lhi * 4;
            #pragma unroll
            for (int cb = 0; cb < 4; ++cb) {
                int c0 = wc * 64 + cb * 16 + llo;
                #pragma unroll
                for (int reg = 0; reg < 4; ++reg)
                    atomicAdd(&part[((size_t)b * CDIM + r0 + reg) * CDIM + c0], acc[rb][cb][reg]);
            }
        }
    } else {
        float* pb = part + ((size_t)split * BATCH + b) * CDIM * CDIM;
        #pragma unroll
        for (int rb = 0; rb < 4; ++rb) {
            int r0 = wr * 64 + rb * 16 + lhi * 4;
            #pragma unroll
            for (int cb = 0; cb < 4; ++cb) {
                int c0 = wc * 64 + cb * 16 + llo;
                #pragma unroll
                for (int reg = 0; reg < 4; ++reg)
                    __builtin_nontemporal_store(acc[rb][cb][reg],
                        &pb[(size_t)(r0 + reg) * CDIM + c0]);
            }
        }
    }
}

// ---------------- K2: SE MLP -> sigmoid gate ----------------
__global__ __launch_bounds__(256) void se_kernel(const float* __restrict__ pooled,
                                                 const float* __restrict__ w1,
                                                 const float* __restrict__ b1,
                                                 const float* __restrict__ w2,
                                                 const float* __restrict__ b2,
                                                 float* __restrict__ gate) {
    int b = blockIdx.x;
    int t = threadIdx.x;
    __shared__ float p[CDIM];
    __shared__ float hid[RDIM];
    p[t] = pooled[b * CDIM + t] * (1.0f / HW);
    __syncthreads();
    if (t < RDIM) {
        float s = b1[t];
        const float* wr = w1 + t * CDIM;
        for (int k = 0; k < CDIM; ++k) s = fmaf(wr[k], p[k], s);
        hid[t] = s > 0.f ? s : 0.f;
    }
    __syncthreads();
    float s = b2[t];
    const float* wr = w2 + t * RDIM;
    #pragma unroll
    for (int k = 0; k < RDIM; ++k) s = fmaf(wr[k], hid[k], s);
    gate[b * CDIM + t] = 1.0f / (1.0f + expf(-s));
}

// ---------------- K3: reduce partials (NT loads) + softmax -> bf16 att image ----
__global__ __launch_bounds__(256) void softmax_kernel(const float* __restrict__ part,
                                                      unsigned short* __restrict__ atts) {
    int row = blockIdx.x;              // b*C + c
    int b = row >> 8, c = row & 255;
    int t = threadIdx.x;               // t = d
    const float* p0 = part + (size_t)row * CDIM + t;
    float val = 0.f;
    #pragma unroll
    for (int s = 0; s < SPLITS; ++s)
        val += __builtin_nontemporal_load(&p0[(size_t)s * BATCH * CDIM * CDIM]);

    float m = val;
    for (int off = 32; off > 0; off >>= 1) m = fminf(m, __shfl_down(m, off));
    __shared__ float redm[4];
    if ((t & 63) == 0) redm[t >> 6] = m;
    __syncthreads();
    float rowmin = fminf(fminf(redm[0], redm[1]), fminf(redm[2], redm[3]));

    float p = expf(rowmin - val);
    float s = p;
    for (int off = 32; off > 0; off >>= 1) s += __shfl_down(s, off);
    __shared__ float reds[4];
    if ((t & 63) == 0) reds[t >> 6] = s;
    __syncthreads();
    float tot = reds[0] + reds[1] + reds[2] + reds[3];

    size_t idx = (size_t)b * 65536 + (size_t)(t >> 6) * 16384 + (bofs(c, t & 63) >> 1);
    atts[idx] = bf16_rne(p / tot);   // normal store: re-read by out_kernel
}

// single-buffer (atomic fallback) softmax: NS=1
__global__ __launch_bounds__(256) void softmax1_kernel(const float* __restrict__ energy,
                                                       unsigned short* __restrict__ atts) {
    int row = blockIdx.x;
    int b = row >> 8, c = row & 255;
    int t = threadIdx.x;
    float val = energy[(size_t)row * CDIM + t];

    float m = val;
    for (int off = 32; off > 0; off >>= 1) m = fminf(m, __shfl_down(m, off));
    __shared__ float redm[4];
    if ((t & 63) == 0) redm[t >> 6] = m;
    __syncthreads();
    float rowmin = fminf(fminf(redm[0], redm[1]), fminf(redm[2], redm[3]));

    float p = expf(rowmin - val);
    float s = p;
    for (int off = 32; off > 0; off >>= 1) s += __shfl_down(s, off);
    __shared__ float reds[4];
    if ((t & 63) == 0) reds[t >> 6] = s;
    __syncthreads();
    float tot = reds[0] + reds[1] + reds[2] + reds[3];

    size_t idx = (size_t)b * 65536 + (size_t)(t >> 6) * 16384 + (bofs(c, t & 63) >> 1);
    atts[idx] = bf16_rne(p / tot);
}

// ---------------- K4: out = gamma * gate * (att @ v) + x  (bf16 MFMA) ----------
// v6: 256 thr (4 waves = 4 c-groups), tile 64n x 256c. LDS = v^T dbuf only
// (2 x 8 KB): att B-frags read DIRECTLY from the pre-swizzled global image
// (L2-hot, per-lane 16B contiguous) -- no att staging, no vmcnt at barriers.
// One lds_barrier per chunk (gram-proven dbuf pattern). Register-limited
// 4 blocks/CU target.
__global__ __launch_bounds__(256, 4) void out_kernel(const unsigned short* __restrict__ atts,
                                                     const float* __restrict__ x,
                                                     const float* __restrict__ gate,
                                                     const float* __restrict__ gammap,
                                                     float* __restrict__ out) {
    __shared__ __align__(16) char lds[16384];   // v^T: 2 x 8 KB

    const int t    = threadIdx.x;
    const int lane = t & 63;
    const int wave = t >> 6;         // 0..3 = c-group
    const int lhi  = lane >> 4, llo = lane & 15;
    const int nblk = blockIdx.x * BN;
    const int b    = blockIdx.y;

    const float* v     = x + (size_t)b * CDIM * HW;
    const char*  attsB = (const char*)atts + (size_t)b * 131072;

    f32x4 acc[4][4];   // [rb over n][cb over c]
    #pragma unroll
    for (int i = 0; i < 4; ++i)
        #pragma unroll
        for (int j = 0; j < 4; ++j)
            acc[i][j] = (f32x4){0.f, 0.f, 0.f, 0.f};

    // v^T staging: thread owns dd-pair (2*ddp, 2*ddp+1) x 8 consecutive n.
    const int ddp = t >> 3;          // 0..31
    const int n8  = (t & 7) * 8;     // 0..56
    float4 vr0a, vr0b, vr1a, vr1b;

    auto load_v = [&](int k0) {
        const float* r0 = v + (size_t)(k0 + 2 * ddp) * HW + nblk + n8;
        vr0a = *(const float4*)r0;
        vr0b = *(const float4*)(r0 + 4);
        vr1a = *(const float4*)(r0 + HW);
        vr1b = *(const float4*)(r0 + HW + 4);
    };

    load_v(0);

    for (int ch = 0; ch < 4; ++ch) {
        char* buf = lds + (ch & 1) * 8192;
        // ---- v^T transpose-writes into buf[p] (safe: buf[p] last read at
        // ch-2; every wave passed barrier ch-1 after lgkmcnt(0)) ----
        {
            const float* f0a = (const float*)&vr0a;
            const float* f0b = (const float*)&vr0b;
            const float* f1a = (const float*)&vr1a;
            const float* f1b = (const float*)&vr1b;
            #pragma unroll
            for (int j = 0; j < 4; ++j) {
                *(unsigned*)(buf + bofs(n8 + j,     2 * ddp)) = pack2(f0a[j], f1a[j]);
                *(unsigned*)(buf + bofs(n8 + 4 + j, 2 * ddp)) = pack2(f0b[j], f1b[j]);
            }
        }
        // ---- issue att B-frags for this chunk (global, L2-hot, in flight) ----
        short8 Bc0[4], Bc1[4];
        #pragma unroll
        for (int cb = 0; cb < 4; ++cb) {
            int c = wave * 64 + cb * 16 + llo;
            Bc0[cb] = *(const short8*)(attsB + ch * 32768 + bofs(c, lhi * 8));
            Bc1[cb] = *(const short8*)(attsB + ch * 32768 + bofs(c, 32 + lhi * 8));
        }
        // ---- issue next v chunk (in flight across barrier) ----
        if (ch < 3) load_v((ch + 1) * BK);

        lds_barrier();   // ds writes visible; globals NOT drained

        #pragma unroll
        for (int ks = 0; ks < 2; ++ks) {
            int kb = ks * 32 + lhi * 8;
            short8 An[4];
            #pragma unroll
            for (int rb = 0; rb < 4; ++rb)   // A = v^T rows (n, 0..63)
                An[rb] = *(const short8*)(buf + bofs(rb * 16 + llo, kb));
            __builtin_amdgcn_s_setprio(1);
            #pragma unroll
            for (int rb = 0; rb < 4; ++rb)
                #pragma unroll
                for (int cb = 0; cb < 4; ++cb)
                    acc[rb][cb] = __builtin_amdgcn_mfma_f32_16x16x32_bf16(
                        An[rb], ks ? Bc1[cb] : Bc0[cb], acc[rb][cb], 0, 0, 0);
            __builtin_amdgcn_s_setprio(0);
        }
    }

    // ---- epilogue: lane owns col c, 4 consecutive n -> float4 NT store ----
    float gm = gammap[0];
    float gv[4];
    #pragma unroll
    for (int cb = 0; cb < 4; ++cb)
        gv[cb] = gm * gate[b * CDIM + wave * 64 + cb * 16 + llo];

    #pragma unroll
    for (int rb = 0; rb < 4; ++rb) {
        int n0 = rb * 16 + lhi * 4;
        #pragma unroll
        for (int cb = 0; cb < 4; ++cb) {
            int c = wave * 64 + cb * 16 + llo;
            size_t base = ((size_t)b * CDIM + c) * HW + nblk + n0;
            f32x4 xv = *(const f32x4*)&x[base];
            f32x4 o;
            o[0] = fmaf(acc[rb][cb][0], gv[cb], xv[0]);
            o[1] = fmaf(acc[rb][cb][1], gv[cb], xv[1]);
            o[2] = fmaf(acc[rb][cb][2], gv[cb], xv[2]);
            o[3] = fmaf(acc[rb][cb][3], gv[cb], xv[3]);
            __builtin_nontemporal_store(o, (f32x4*)&out[base]);
        }
    }
}

extern "C" void kernel_launch(void* const* d_in, const int* in_sizes, int n_in,
                              void* d_out, int out_size, void* d_ws, size_t ws_size,
                              hipStream_t stream) {
    const float* x     = (const float*)d_in[0];
    const float* gamma = (const float*)d_in[1];
    const float* w1    = (const float*)d_in[2];
    const float* b1    = (const float*)d_in[3];
    const float* w2    = (const float*)d_in[4];
    const float* b2    = (const float*)d_in[5];
    float* out = (float*)d_out;

    const size_t ee        = (size_t)BATCH * CDIM * CDIM;   // 1 Mi elems
    const size_t partElems = (size_t)SPLITS * ee;           // 16 Mi floats = 64 MB
    const size_t needPart  = partElems * sizeof(float) + ee * 2 + 2 * BATCH * CDIM * sizeof(float);

    if (ws_size >= needPart) {
        float*          part   = (float*)d_ws;                                // 64 MB
        unsigned short* atts   = (unsigned short*)(part + partElems);         // 2 MB
        float*          pooled = (float*)(atts + ee);
        float*          gate   = pooled + BATCH * CDIM;

        hipMemsetAsync(pooled, 0, (size_t)BATCH * CDIM * sizeof(float), stream);
        gram_kernel<false><<<dim3(SPLITS, BATCH), 1024, 0, stream>>>(x, part, pooled);
        se_kernel<<<BATCH, 256, 0, stream>>>(pooled, w1, b1, w2, b2, gate);
        softmax_kernel<<<BATCH * CDIM, 256, 0, stream>>>(part, atts);
        out_kernel<<<dim3(HW / BN, BATCH), 256, 0, stream>>>(atts, x, gate, gamma, out);
    } else {
        float*          energy = (float*)d_ws;                                // 4 MB
        unsigned short* atts   = (unsigned short*)(energy + ee);              // 2 MB
        float*          pooled = (float*)(atts + ee);
        float*          gate   = pooled + BATCH * CDIM;

        hipMemsetAsync(energy, 0, ee * sizeof(float), stream);
        hipMemsetAsync(pooled, 0, (size_t)BATCH * CDIM * sizeof(float), stream);
        gram_kernel<true><<<dim3(SPLITS, BATCH), 1024, 0, stream>>>(x, energy, pooled);
        se_kernel<<<BATCH, 256, 0, stream>>>(pooled, w1, b1, w2, b2, gate);
        softmax1_kernel<<<BATCH * CDIM, 256, 0, stream>>>(energy, atts);
        out_kernel<<<dim3(HW / BN, BATCH), 256, 0, stream>>>(atts, x, gate, gamma, out);
    }
}

// Round 19
// 150.998 us; speedup vs baseline: 1.6256x; 1.6256x over previous
//
#include <hip/hip_runtime.h>
#include <math.h>

#define BATCH 16
#define CDIM 256
#define HW 9216
#define RDIM 32
#define SPLITS 16
#define KSLAB (HW / SPLITS)   /* 576 */
#define KCH 32                /* gram k-columns per chunk */
#define NCH (KSLAB / KCH)     /* 18, even */

#define BN 64                 /* out_kernel n-tile */
#define VOFF 16384            /* v^T tile byte offset inside shared block */

typedef __attribute__((ext_vector_type(8))) short short8;
typedef __attribute__((ext_vector_type(4))) short short4_t;
typedef __attribute__((ext_vector_type(4))) float f32x4;
typedef __attribute__((ext_vector_type(8))) _Float16 half8;
typedef __attribute__((ext_vector_type(4))) _Float16 half4;

__device__ __forceinline__ unsigned short bf16_rne(float x) {
    union { float f; unsigned u; } a; a.f = x;
    return (unsigned short)((a.u + 0x7fffu + ((a.u >> 16) & 1u)) >> 16);
}
__device__ __forceinline__ unsigned pack2(float lo, float hi) {
    return (unsigned)bf16_rne(lo) | ((unsigned)bf16_rne(hi) << 16);
}

// Non-draining barrier: ds ops visible, global loads STAY IN FLIGHT.
__device__ __forceinline__ void lds_barrier() {
    asm volatile("s_waitcnt lgkmcnt(0)" ::: "memory");
    __builtin_amdgcn_s_barrier();
}

// async 16B global->LDS copy
__device__ __forceinline__ void gload16(const void* g, void* l) {
    __builtin_amdgcn_global_load_lds(
        (const __attribute__((address_space(1))) unsigned*)g,
        (__attribute__((address_space(3))) unsigned*)l, 16, 0, 0);
}

// gram fp16 tile [256 rows][32 k], row stride 64 B (2-way max conflicts).
// Returns _Float16 element index.
__device__ __forceinline__ int gswz16(int row, int k) {
    int byte = (row << 6) + (k << 1);
    byte ^= (((row >> 1) ^ (row >> 3)) & 3) << 4;
    return byte >> 1;
}
// swizzle for [*][64] bf16 tiles (row stride 128 B); BYTE offset.
__device__ __forceinline__ int bofs(int row, int k) {
    return (((row) << 7) | ((k) << 1)) ^ (((row ^ (row >> 2)) & 7) << 4);
}
// swizzle for [*][32] bf16 tiles (row stride 64 B); BYTE offset.
__device__ __forceinline__ int aofs(int row, int k) {
    int byte = (row << 6) + (k << 1);
    byte ^= (((row >> 1) ^ (row >> 3)) & 3) << 4;
    return byte;
}

// ---------------- K1: energy partials = v v^T (split-K, fp16 MFMA) ----------
// R17-proven: packed fp16 NT partial stores; atomic fallback (fp32 energy).
template <bool ATOMIC>
__global__ __launch_bounds__(1024) void gram_kernel(const float* __restrict__ x,
                                                    float* __restrict__ energyA,
                                                    _Float16* __restrict__ part16,
                                                    float* __restrict__ pooled) {
    int split = blockIdx.x;
    int b     = blockIdx.y;
    const float* v = x + (size_t)b * CDIM * HW;
    int kbase0 = split * KSLAB;

    __shared__ _Float16 lds[2][CDIM * KCH];   // 2 x 16 KB

    int t    = threadIdx.x;
    int row  = t >> 2;
    int kq   = t & 3;
    int lane = t & 63;
    int wave = t >> 6;
    int wr   = wave >> 2, wc = wave & 3;
    int lhi  = lane >> 4, llo = lane & 15;

    const float4* vrow = (const float4*)(v + (size_t)row * HW);

    f32x4 acc[4][4];
    #pragma unroll
    for (int i = 0; i < 4; ++i)
        #pragma unroll
        for (int j = 0; j < 4; ++j)
            acc[i][j] = (f32x4){0.f, 0.f, 0.f, 0.f};

    float psum = 0.f;
    float4 fa0, fa1, fb0, fb1;

    {
        int kb0 = kbase0;
        fa0 = vrow[(kb0 >> 2) + kq * 2];
        fa1 = vrow[(kb0 >> 2) + kq * 2 + 1];
        int kb1 = kbase0 + KCH;
        fb0 = vrow[(kb1 >> 2) + kq * 2];
        fb1 = vrow[(kb1 >> 2) + kq * 2 + 1];
    }

    auto body = [&](float4& g0, float4& g1, _Float16* buf, int ch) {
        float vals[8] = { g0.x, g0.y, g0.z, g0.w, g1.x, g1.y, g1.z, g1.w };
        half8 h;
        #pragma unroll
        for (int j = 0; j < 8; ++j) {
            psum += vals[j];
            h[j] = (_Float16)vals[j];
        }
        *(half8*)&buf[gswz16(row, kq * 8)] = h;
        if (ch + 2 < NCH) {
            int kb = kbase0 + (ch + 2) * KCH;
            g0 = vrow[(kb >> 2) + kq * 2];
            g1 = vrow[(kb >> 2) + kq * 2 + 1];
        }
        lds_barrier();

        half8 A[4], B[4];
        #pragma unroll
        for (int rb = 0; rb < 4; ++rb)
            A[rb] = *(const half8*)&buf[gswz16(wr * 64 + rb * 16 + llo, lhi * 8)];
        #pragma unroll
        for (int cb = 0; cb < 4; ++cb)
            B[cb] = *(const half8*)&buf[gswz16(wc * 64 + cb * 16 + llo, lhi * 8)];

        __builtin_amdgcn_s_setprio(1);
        #pragma unroll
        for (int rb = 0; rb < 4; ++rb)
            #pragma unroll
            for (int cb = 0; cb < 4; ++cb)
                acc[rb][cb] = __builtin_amdgcn_mfma_f32_16x16x32_f16(A[rb], B[cb], acc[rb][cb], 0, 0, 0);
        __builtin_amdgcn_s_setprio(0);
    };

    #pragma unroll 1
    for (int it = 0; it < NCH / 2; ++it) {
        body(fa0, fa1, (_Float16*)lds[0], it * 2);
        body(fb0, fb1, (_Float16*)lds[1], it * 2 + 1);
    }

    psum += __shfl_xor(psum, 1);
    psum += __shfl_xor(psum, 2);
    if (kq == 0) atomicAdd(&pooled[b * CDIM + row], psum);

    if (ATOMIC) {
        #pragma unroll
        for (int rb = 0; rb < 4; ++rb) {
            int r0 = wr * 64 + rb * 16 + lhi * 4;
            #pragma unroll
            for (int cb = 0; cb < 4; ++cb) {
                int c0 = wc * 64 + cb * 16 + llo;
                #pragma unroll
                for (int reg = 0; reg < 4; ++reg)
                    atomicAdd(&energyA[((size_t)b * CDIM + r0 + reg) * CDIM + c0], acc[rb][cb][reg]);
            }
        }
    } else {
        _Float16* pb = part16 + ((size_t)split * BATCH + b) * CDIM * CDIM;
        #pragma unroll
        for (int rb = 0; rb < 4; ++rb) {
            int rq = wr * 16 + rb * 4 + lhi;          // row-quad index 0..63
            #pragma unroll
            for (int cb = 0; cb < 4; ++cb) {
                int d = wc * 64 + cb * 16 + llo;      // col (d) 0..255
                half4 hv;
                hv[0] = (_Float16)acc[rb][cb][0];
                hv[1] = (_Float16)acc[rb][cb][1];
                hv[2] = (_Float16)acc[rb][cb][2];
                hv[3] = (_Float16)acc[rb][cb][3];
                __builtin_nontemporal_store(hv,
                    (half4*)(pb + ((size_t)rq * CDIM + d) * 4));
            }
        }
    }
}

// ---------------- K2: SE MLP -> sigmoid gate ----------------
__global__ __launch_bounds__(256) void se_kernel(const float* __restrict__ pooled,
                                                 const float* __restrict__ w1,
                                                 const float* __restrict__ b1,
                                                 const float* __restrict__ w2,
                                                 const float* __restrict__ b2,
                                                 float* __restrict__ gate) {
    int b = blockIdx.x;
    int t = threadIdx.x;
    __shared__ float p[CDIM];
    __shared__ float hid[RDIM];
    p[t] = pooled[b * CDIM + t] * (1.0f / HW);
    __syncthreads();
    if (t < RDIM) {
        float s = b1[t];
        const float* wr = w1 + t * CDIM;
        for (int k = 0; k < CDIM; ++k) s = fmaf(wr[k], p[k], s);
        hid[t] = s > 0.f ? s : 0.f;
    }
    __syncthreads();
    float s = b2[t];
    const float* wr = w2 + t * RDIM;
    #pragma unroll
    for (int k = 0; k < RDIM; ++k) s = fmaf(wr[k], hid[k], s);
    gate[b * CDIM + t] = 1.0f / (1.0f + expf(-s));
}

// ---------------- K3: reduce fp16 partials + softmax -> bf16 att image ----------
// att image: per (b, K-step kh of 32 d): 16 KB block, byte = aofs(c, d&31).
// 8 blocks of 16 KB per batch (128 KB/batch total).
__global__ __launch_bounds__(256) void softmax_kernel(const _Float16* __restrict__ part16,
                                                      unsigned short* __restrict__ atts) {
    int blk = blockIdx.x;              // b*64 + cq
    int b = blk >> 6, cq = blk & 63;
    int t = threadIdx.x;               // d
    int lane = t & 63, w = t >> 6;

    float val[4] = {0.f, 0.f, 0.f, 0.f};
    const _Float16* p0 = part16 + ((size_t)cq * CDIM + t) * 4;
    #pragma unroll
    for (int s = 0; s < SPLITS; ++s) {
        half4 hv = __builtin_nontemporal_load(
            (const half4*)(p0 + ((size_t)(s * BATCH + b)) * CDIM * CDIM));
        val[0] += (float)hv[0];
        val[1] += (float)hv[1];
        val[2] += (float)hv[2];
        val[3] += (float)hv[3];
    }

    __shared__ float redm[4][4], reds[4][4];
    #pragma unroll
    for (int j = 0; j < 4; ++j) {
        float m = val[j];
        for (int off = 32; off > 0; off >>= 1) m = fminf(m, __shfl_down(m, off));
        if (lane == 0) redm[j][w] = m;
    }
    __syncthreads();
    float p[4];
    #pragma unroll
    for (int j = 0; j < 4; ++j) {
        float rowmin = fminf(fminf(redm[j][0], redm[j][1]), fminf(redm[j][2], redm[j][3]));
        p[j] = expf(rowmin - val[j]);
        float s = p[j];
        for (int off = 32; off > 0; off >>= 1) s += __shfl_down(s, off);
        if (lane == 0) reds[j][w] = s;
    }
    __syncthreads();
    #pragma unroll
    for (int j = 0; j < 4; ++j) {
        float tot = reds[j][0] + reds[j][1] + reds[j][2] + reds[j][3];
        int c = cq * 4 + j;
        size_t idx = (size_t)b * 131072 + (size_t)(t >> 5) * 16384 + aofs(c, t & 31);
        *(unsigned short*)((char*)atts + idx) = bf16_rne(p[j] / tot);
    }
}

// single-buffer (atomic fallback) softmax: NS=1, fp32 energy
__global__ __launch_bounds__(256) void softmax1_kernel(const float* __restrict__ energy,
                                                       unsigned short* __restrict__ atts) {
    int row = blockIdx.x;
    int b = row >> 8, c = row & 255;
    int t = threadIdx.x;
    float val = energy[(size_t)row * CDIM + t];

    float m = val;
    for (int off = 32; off > 0; off >>= 1) m = fminf(m, __shfl_down(m, off));
    __shared__ float redm[4];
    if ((t & 63) == 0) redm[t >> 6] = m;
    __syncthreads();
    float rowmin = fminf(fminf(redm[0], redm[1]), fminf(redm[2], redm[3]));

    float p = expf(rowmin - val);
    float s = p;
    for (int off = 32; off > 0; off >>= 1) s += __shfl_down(s, off);
    __shared__ float reds[4];
    if ((t & 63) == 0) reds[t >> 6] = s;
    __syncthreads();
    float tot = reds[0] + reds[1] + reds[2] + reds[3];

    size_t idx = (size_t)b * 131072 + (size_t)(t >> 5) * 16384 + aofs(c, t & 31);
    *(unsigned short*)((char*)atts + idx) = bf16_rne(p / tot);
}

// ---------------- K4: out = gamma * gate * (att @ v) + x  (bf16 MFMA) ----------
// v7: 24 KB LDS (att 16 KB half-image per K-step of 32 + v^T 8 KB) ->
// 4 blocks/CU (LDS 96 KB; regs 16 waves x 128 = exact file fit).
// 8 K-steps; att staged via 4x gload16; v^T (64 dd) staged every other step.
__global__ __launch_bounds__(256, 4) void out_kernel(const unsigned short* __restrict__ atts,
                                                     const float* __restrict__ x,
                                                     const float* __restrict__ gate,
                                                     const float* __restrict__ gammap,
                                                     float* __restrict__ out) {
    __shared__ __align__(16) char lds[24576];   // att 16KB @0, v^T 8KB @VOFF

    const int t    = threadIdx.x;
    const int lane = t & 63;
    const int wave = t >> 6;         // 0..3 = c-group
    const int lhi  = lane >> 4, llo = lane & 15;
    const int nblk = blockIdx.x * BN;
    const int b    = blockIdx.y;

    const float* v     = x + (size_t)b * CDIM * HW;
    const char*  attsB = (const char*)atts + (size_t)b * 131072;

    f32x4 acc[4][4];   // [rb over n][cb over c]
    #pragma unroll
    for (int i = 0; i < 4; ++i)
        #pragma unroll
        for (int j = 0; j < 4; ++j)
            acc[i][j] = (f32x4){0.f, 0.f, 0.f, 0.f};

    const int ddp = t >> 3;          // 0..31
    const int n8  = (t & 7) * 8;     // 0..56
    float4 vr0a, vr0b, vr1a, vr1b;

    auto load_v = [&](int k0) {
        const float* r0 = v + (size_t)(k0 + 2 * ddp) * HW + nblk + n8;
        vr0a = *(const float4*)r0;
        vr0b = *(const float4*)(r0 + 4);
        vr1a = *(const float4*)(r0 + HW);
        vr1b = *(const float4*)(r0 + HW + 4);
    };

    load_v(0);

    for (int kh = 0; kh < 8; ++kh) {       // K-step of 32 d-columns
        __syncthreads();   // prior step's frag reads done
        // ---- att 16KB block for this K-step ----
        #pragma unroll
        for (int i = 0; i < 4; ++i)
            gload16(attsB + kh * 16384 + i * 4096 + t * 16, lds + i * 4096 + t * 16);
        // ---- v^T tile: stage 64 dd-columns every OTHER step ----
        if ((kh & 1) == 0) {
            const float* f0a = (const float*)&vr0a;
            const float* f0b = (const float*)&vr0b;
            const float* f1a = (const float*)&vr1a;
            const float* f1b = (const float*)&vr1b;
            #pragma unroll
            for (int j = 0; j < 4; ++j) {
                *(unsigned*)(lds + VOFF + bofs(n8 + j,     2 * ddp)) = pack2(f0a[j], f1a[j]);
                *(unsigned*)(lds + VOFF + bofs(n8 + 4 + j, 2 * ddp)) = pack2(f0b[j], f1b[j]);
            }
        }
        __syncthreads();   // staged (att gloads + v ds_writes drained)

        if (kh < 7 && (kh & 1) == 1) load_v((kh + 1) * 32);  // prefetch next v tile

        // ---- MFMA: one K-step of 32 ----
        {
            int kb = (kh & 1) * 32 + lhi * 8;   // col within the 64-wide v^T tile
            short8 An[4], Bc[4];
            #pragma unroll
            for (int rb = 0; rb < 4; ++rb)   // A = v^T rows (n, 0..63)
                An[rb] = *(const short8*)(lds + VOFF + bofs(rb * 16 + llo, kb));
            #pragma unroll
            for (int cb = 0; cb < 4; ++cb)   // B = att rows (c, wave's 64)
                Bc[cb] = *(const short8*)(lds + aofs(wave * 64 + cb * 16 + llo, lhi * 8));
            #pragma unroll
            for (int rb = 0; rb < 4; ++rb)
                #pragma unroll
                for (int cb = 0; cb < 4; ++cb)
                    acc[rb][cb] = __builtin_amdgcn_mfma_f32_16x16x32_bf16(An[rb], Bc[cb], acc[rb][cb], 0, 0, 0);
        }
    }

    float gm = gammap[0];
    float gv[4];
    #pragma unroll
    for (int cb = 0; cb < 4; ++cb)
        gv[cb] = gm * gate[b * CDIM + wave * 64 + cb * 16 + llo];

    #pragma unroll
    for (int rb = 0; rb < 4; ++rb) {
        int n0 = rb * 16 + lhi * 4;
        #pragma unroll
        for (int cb = 0; cb < 4; ++cb) {
            int c = wave * 64 + cb * 16 + llo;
            size_t base = ((size_t)b * CDIM + c) * HW + nblk + n0;
            f32x4 xv = *(const f32x4*)&x[base];
            f32x4 o;
            o[0] = fmaf(acc[rb][cb][0], gv[cb], xv[0]);
            o[1] = fmaf(acc[rb][cb][1], gv[cb], xv[1]);
            o[2] = fmaf(acc[rb][cb][2], gv[cb], xv[2]);
            o[3] = fmaf(acc[rb][cb][3], gv[cb], xv[3]);
            __builtin_nontemporal_store(o, (f32x4*)&out[base]);
        }
    }
}

extern "C" void kernel_launch(void* const* d_in, const int* in_sizes, int n_in,
                              void* d_out, int out_size, void* d_ws, size_t ws_size,
                              hipStream_t stream) {
    const float* x     = (const float*)d_in[0];
    const float* gamma = (const float*)d_in[1];
    const float* w1    = (const float*)d_in[2];
    const float* b1    = (const float*)d_in[3];
    const float* w2    = (const float*)d_in[4];
    const float* b2    = (const float*)d_in[5];
    float* out = (float*)d_out;

    const size_t ee       = (size_t)BATCH * CDIM * CDIM;    // 1 Mi elems
    const size_t partHalf = (size_t)SPLITS * ee;            // 16 Mi fp16 = 32 MB
    const size_t needPart = partHalf * 2 + ee * 2 + 2 * BATCH * CDIM * sizeof(float);

    if (ws_size >= needPart) {
        _Float16*       part16 = (_Float16*)d_ws;                             // 32 MB
        unsigned short* atts   = (unsigned short*)(part16 + partHalf);        // 2 MB
        float*          pooled = (float*)(atts + ee);
        float*          gate   = pooled + BATCH * CDIM;

        hipMemsetAsync(pooled, 0, (size_t)BATCH * CDIM * sizeof(float), stream);
        gram_kernel<false><<<dim3(SPLITS, BATCH), 1024, 0, stream>>>(x, nullptr, part16, pooled);
        se_kernel<<<BATCH, 256, 0, stream>>>(pooled, w1, b1, w2, b2, gate);
        softmax_kernel<<<BATCH * 64, 256, 0, stream>>>(part16, atts);
        out_kernel<<<dim3(HW / BN, BATCH), 256, 0, stream>>>(atts, x, gate, gamma, out);
    } else {
        float*          energy = (float*)d_ws;                                // 4 MB
        unsigned short* atts   = (unsigned short*)(energy + ee);              // 2 MB
        float*          pooled = (float*)(atts + ee);
        float*          gate   = pooled + BATCH * CDIM;

        hipMemsetAsync(energy, 0, ee * sizeof(float), stream);
        hipMemsetAsync(pooled, 0, (size_t)BATCH * CDIM * sizeof(float), stream);
        gram_kernel<true><<<dim3(SPLITS, BATCH), 1024, 0, stream>>>(x, energy, nullptr, pooled);
        se_kernel<<<BATCH, 256, 0, stream>>>(pooled, w1, b1, w2, b2, gate);
        softmax1_kernel<<<BATCH * CDIM, 256, 0, stream>>>(energy, atts);
        out_kernel<<<dim3(HW / BN, BATCH), 256, 0, stream>>>(atts, x, gate, gamma, out);
    }
}